// Round 1
// baseline (2436.590 us; speedup 1.0000x reference)
//
#include <hip/hip_runtime.h>
#include <cstdint>

#define B_ 16
#define C_ 16
#define H_ 128
#define W_ 128
#define HID_ 128
#define K_ 48
#define NSTEPS 24
#define THR 0.1f
#define TS 16
#define TP 18
#define FRAMES 25
#define CHW (C_*H_*W_)
#define HW (H_*W_)

// frame 0 = input x, copied batch-wise into the strided output layout
__global__ void frame0_copy(const float4* __restrict__ x, float4* __restrict__ out) {
    int idx = blockIdx.x * 256 + threadIdx.x;      // over B*C*H*W/4 = 1,048,576
    int per_b = CHW / 4;
    int b = idx / per_b;
    int r = idx - b * per_b;
    out[(size_t)b * (FRAMES * CHW / 4) + r] = x[idx];
}

// w2 (C, HID) -> w2t (HID, C) so the h-loop reads 16 contiguous dwords
__global__ void w2_transpose(const float* __restrict__ w2, float* __restrict__ w2t) {
    int i = blockIdx.x * 256 + threadIdx.x;        // 2048
    int c = i >> 7, h = i & 127;
    w2t[h * C_ + c] = w2[i];
}

// stepA: read frame s, LDS tile + 1-halo (wrap), pre-life, depthwise conv,
// MLP 48->128->16, write UNMASKED x+delta to x1 and pre-life to premask.
__global__ __launch_bounds__(256) void stepA(
    const float* __restrict__ frames,   // d_out base
    const float* __restrict__ w1,       // (128,48) row-major
    const float* __restrict__ b1,       // (128)
    const float* __restrict__ w2t,      // (128,16)
    float* __restrict__ x1,
    float* __restrict__ premask,
    int s)
{
    __shared__ float xs[C_][TP][TP];
    const int b = blockIdx.z;
    const int ty0 = blockIdx.y * TS, tx0 = blockIdx.x * TS;
    const int tid = threadIdx.x;
    const float* xin = frames + ((size_t)b * FRAMES + s) * CHW;

    // cooperative halo load with wrap
    for (int p = tid; p < TP * TP; p += 256) {
        int iy = p / TP, ix = p - iy * TP;
        int gy = (ty0 + iy - 1) & (H_ - 1);
        int gx = (tx0 + ix - 1) & (W_ - 1);
        const float* src = xin + gy * W_ + gx;
        #pragma unroll
        for (int c = 0; c < C_; ++c)
            xs[c][iy][ix] = src[c * HW];
    }
    __syncthreads();

    const int ly = tid >> 4, lx = tid & 15;

    // pre_life: 3x3 max over channel 0 of padded x
    float m = -1e30f;
    #pragma unroll
    for (int dy = 0; dy < 3; ++dy)
        #pragma unroll
        for (int dx = 0; dx < 3; ++dx)
            m = fmaxf(m, xs[0][ly + dy][lx + dx]);
    const float pre = (m > THR) ? 1.0f : 0.0f;

    // depthwise conv -> d[48], interleaved [id, sobel_x, sobel_y] per channel
    float d[K_];
    #pragma unroll
    for (int c = 0; c < C_; ++c) {
        float a00 = xs[c][ly][lx],     a01 = xs[c][ly][lx + 1],     a02 = xs[c][ly][lx + 2];
        float a10 = xs[c][ly + 1][lx],                              a12 = xs[c][ly + 1][lx + 2];
        float a20 = xs[c][ly + 2][lx], a21 = xs[c][ly + 2][lx + 1], a22 = xs[c][ly + 2][lx + 2];
        float a11 = xs[c][ly + 1][lx + 1];
        d[3 * c]     = a11;
        d[3 * c + 1] = (a02 - a00 + 2.0f * (a12 - a10) + a22 - a20) * 0.125f;
        d[3 * c + 2] = (a00 + 2.0f * a01 + a02 - a20 - 2.0f * a21 - a22) * 0.125f;
    }

    // MLP: h = relu(W1 d + b1); delta = W2 h. Weights via wave-uniform
    // (scalar) loads; 4 accumulators to hide FMA latency.
    float acc[C_];
    #pragma unroll
    for (int c = 0; c < C_; ++c) acc[c] = 0.0f;

    #pragma unroll 2
    for (int h = 0; h < HID_; ++h) {
        const float* wr = w1 + h * K_;
        float s0 = 0.f, s1 = 0.f, s2 = 0.f, s3 = 0.f;
        #pragma unroll
        for (int k = 0; k < K_; k += 4) {
            s0 = fmaf(wr[k + 0], d[k + 0], s0);
            s1 = fmaf(wr[k + 1], d[k + 1], s1);
            s2 = fmaf(wr[k + 2], d[k + 2], s2);
            s3 = fmaf(wr[k + 3], d[k + 3], s3);
        }
        float hv = fmaxf((s0 + s1) + (s2 + s3) + b1[h], 0.0f);
        const float* wc = w2t + h * C_;
        #pragma unroll
        for (int c = 0; c < C_; ++c) acc[c] = fmaf(wc[c], hv, acc[c]);
    }

    const int y = ty0 + ly, x = tx0 + lx;
    float* xo = x1 + (size_t)b * CHW + y * W_ + x;
    #pragma unroll
    for (int c = 0; c < C_; ++c)
        xo[c * HW] = d[3 * c] + acc[c];         // d[3c] is the identity tap = old x
    premask[b * HW + y * W_ + x] = pre;
}

// stepB: post-life on unmasked x1 channel 0 (wrap), combine with pre-life,
// write masked state as frame s+1.
__global__ __launch_bounds__(256) void stepB(
    const float* __restrict__ x1,
    const float* __restrict__ premask,
    float* __restrict__ frames,
    int s)
{
    int idx = blockIdx.x * 256 + threadIdx.x;   // over B*H*W = 262144
    int b = idx >> 14;
    int yx = idx & (HW - 1);
    int y = yx >> 7, x = yx & (W_ - 1);
    const float* c0 = x1 + (size_t)b * CHW;
    float m = -1e30f;
    #pragma unroll
    for (int dy = -1; dy <= 1; ++dy) {
        int gy = (y + dy) & (H_ - 1);
        #pragma unroll
        for (int dx = -1; dx <= 1; ++dx) {
            int gx = (x + dx) & (W_ - 1);
            m = fmaxf(m, c0[gy * W_ + gx]);
        }
    }
    float life = (m > THR && premask[idx] != 0.0f) ? 1.0f : 0.0f;
    const float* xi = x1 + (size_t)b * CHW + yx;
    float* xo = frames + ((size_t)b * FRAMES + s + 1) * CHW + yx;
    #pragma unroll
    for (int c = 0; c < C_; ++c)
        xo[c * HW] = xi[c * HW] * life;
}

extern "C" void kernel_launch(void* const* d_in, const int* in_sizes, int n_in,
                              void* d_out, int out_size, void* d_ws, size_t ws_size,
                              hipStream_t stream)
{
    const float* x  = (const float*)d_in[0];
    const float* w1 = (const float*)d_in[1];
    const float* b1 = (const float*)d_in[2];
    const float* w2 = (const float*)d_in[3];
    // d_in[4] = steps (fixed at 24 for this problem)
    float* out = (float*)d_out;

    float* x1      = (float*)d_ws;                                        // 16 MB
    float* premask = (float*)((char*)d_ws + (size_t)B_ * CHW * 4);        // 1 MB
    float* w2t     = (float*)((char*)d_ws + (size_t)B_ * CHW * 4 + (size_t)B_ * HW * 4);

    w2_transpose<<<8, 256, 0, stream>>>(w2, w2t);
    frame0_copy<<<(B_ * CHW / 4) / 256, 256, 0, stream>>>((const float4*)x, (float4*)out);

    for (int s = 0; s < NSTEPS; ++s) {
        stepA<<<dim3(W_ / TS, H_ / TS, B_), 256, 0, stream>>>(out, w1, b1, w2t, x1, premask, s);
        stepB<<<(B_ * HW) / 256, 256, 0, stream>>>(x1, premask, out, s);
    }
}